// Round 1
// baseline (306.579 us; speedup 1.0000x reference)
//
#include <hip/hip_runtime.h>

// Problem: out = mean_i( rank_of_diag(cos_sim(x1, x2))_i < nper ), nper = S/100 + 1.
// rank_i = #{ j : dot(x1_i,x2_j)*inv||x2_j|| > dot(x1_i,x2_i)*inv||x2_i|| }  (ties measure-zero, j==i excluded)
// K = 128 fixed. All fp32 (precision: one-row-flip tolerance only).

#define KDIM 128
#define BM 128
#define BN 128
#define BK 32
#define LSTR (BM + 4)   // padded LDS stride (4-way max conflict on staged writes)

// ---------- Kernel A: per-row 1/||x2||, diag threshold, zero counters ----------
// One wave per row: 64 lanes x float2 = 128 elements.
__global__ __launch_bounds__(256) void prep_kernel(
    const float* __restrict__ x1, const float* __restrict__ x2,
    float* __restrict__ invn, float* __restrict__ thr,
    int* __restrict__ row_count, int B, int S)
{
    const int wave = threadIdx.x >> 6;
    const int lane = threadIdx.x & 63;
    const int row = blockIdx.x * 4 + wave;
    if (row >= S && row >= B) return;

    float s22 = 0.f, s12 = 0.f;
    if (row < S) {
        const float2* p1 = (const float2*)&x1[(size_t)row * KDIM];
        const float2* p2 = (const float2*)&x2[(size_t)row * KDIM];
        float2 a = p1[lane];
        float2 b = p2[lane];
        s22 = fmaf(b.x, b.x, b.y * b.y);
        s12 = fmaf(a.x, b.x, a.y * b.y);
    }
    #pragma unroll
    for (int m = 32; m > 0; m >>= 1) {
        s22 += __shfl_xor(s22, m);
        s12 += __shfl_xor(s12, m);
    }
    if (lane == 0) {
        if (row < S) {
            float iv = rsqrtf(s22);
            invn[row] = iv;
            if (row < B) thr[row] = s12 * iv;
        }
        if (row < B) row_count[row] = 0;
    }
}

// ---------- Kernel B: tiled fp32 GEMM + compare-count ----------
// 128x128 tile, 256 threads, 8x8 micro-tile/thread, K staged in BK=32 chunks.
__global__ __launch_bounds__(256) void count_kernel(
    const float* __restrict__ x1, const float* __restrict__ x2,
    const float* __restrict__ invn, const float* __restrict__ thr,
    int* __restrict__ row_count, int B, int S)
{
    __shared__ float As[BK][LSTR];   // As[k][i]  (transposed for float4 fragment reads)
    __shared__ float Bs[BK][LSTR];   // Bs[k][j]
    __shared__ int   cnt_s[BM];

    const int tid  = threadIdx.x;
    const int row0 = blockIdx.y * BM;
    const int col0 = blockIdx.x * BN;

    const int ty = tid >> 4;         // 0..15
    const int tx = tid & 15;         // 0..15
    const int tr = ty * 8;           // local row base
    const int tc = tx * 8;           // local col base

    // staging coords: each thread loads 4 float4 per operand per chunk
    const int sr = tid >> 3;         // 0..31 (row within 32-row group)
    const int sc = (tid & 7) * 4;    // 0,4,...,28 (col within BK)

    if (tid < BM) cnt_s[tid] = 0;

    float acc[8][8];
    #pragma unroll
    for (int i = 0; i < 8; i++)
        #pragma unroll
        for (int j = 0; j < 8; j++) acc[i][j] = 0.f;

    for (int kc = 0; kc < KDIM; kc += BK) {
        __syncthreads();
        #pragma unroll
        for (int q = 0; q < 4; q++) {
            const int r = sr + 32 * q;
            float4 a = *(const float4*)&x1[(size_t)(row0 + r) * KDIM + kc + sc];
            float4 b = *(const float4*)&x2[(size_t)(col0 + r) * KDIM + kc + sc];
            As[sc + 0][r] = a.x; As[sc + 1][r] = a.y; As[sc + 2][r] = a.z; As[sc + 3][r] = a.w;
            Bs[sc + 0][r] = b.x; Bs[sc + 1][r] = b.y; Bs[sc + 2][r] = b.z; Bs[sc + 3][r] = b.w;
        }
        __syncthreads();

        #pragma unroll
        for (int k = 0; k < BK; k++) {
            float a[8], b[8];
            *(float4*)&a[0] = *(const float4*)&As[k][tr];
            *(float4*)&a[4] = *(const float4*)&As[k][tr + 4];
            *(float4*)&b[0] = *(const float4*)&Bs[k][tc];
            *(float4*)&b[4] = *(const float4*)&Bs[k][tc + 4];
            #pragma unroll
            for (int i = 0; i < 8; i++)
                #pragma unroll
                for (int j = 0; j < 8; j++)
                    acc[i][j] = fmaf(a[i], b[j], acc[i][j]);
        }
    }

    // epilogue: normalize by 1/||x2_j||, compare vs diag threshold, count
    float invn_l[8], thr_l[8];
    #pragma unroll
    for (int j = 0; j < 8; j++) invn_l[j] = invn[col0 + tc + j];
    #pragma unroll
    for (int i = 0; i < 8; i++) thr_l[i] = thr[row0 + tr + i];

    #pragma unroll
    for (int i = 0; i < 8; i++) {
        const int gi = row0 + tr + i;
        int c = 0;
        #pragma unroll
        for (int j = 0; j < 8; j++) {
            const int gj = col0 + tc + j;
            const float s = acc[i][j] * invn_l[j];
            c += (s > thr_l[i] && gj != gi) ? 1 : 0;
        }
        if (c) atomicAdd(&cnt_s[tr + i], c);
    }
    __syncthreads();
    if (tid < BM) {
        int v = cnt_s[tid];
        if (v) atomicAdd(&row_count[row0 + tid], v);
    }
}

// ---------- Kernel C: final reduction ----------
__global__ __launch_bounds__(1024) void finalize_kernel(
    const int* __restrict__ row_count, float* __restrict__ out, int B, int nper)
{
    __shared__ int wsum[16];
    const int t = threadIdx.x;
    int c = 0;
    for (int i = t; i < B; i += 1024) c += (row_count[i] < nper) ? 1 : 0;
    #pragma unroll
    for (int m = 32; m > 0; m >>= 1) c += __shfl_xor(c, m);
    if ((t & 63) == 0) wsum[t >> 6] = c;
    __syncthreads();
    if (t == 0) {
        int tot = 0;
        #pragma unroll
        for (int w = 0; w < 16; w++) tot += wsum[w];
        out[0] = (float)tot / (float)B;
    }
}

extern "C" void kernel_launch(void* const* d_in, const int* in_sizes, int n_in,
                              void* d_out, int out_size, void* d_ws, size_t ws_size,
                              hipStream_t stream)
{
    const float* x1 = (const float*)d_in[0];
    const float* x2 = (const float*)d_in[1];
    const int B = in_sizes[0] / KDIM;     // 8192
    const int S = in_sizes[1] / KDIM;     // 8192
    const int nper = S / 100 + 1;         // int(S*1/100)+1 = 82

    float* invn      = (float*)d_ws;
    float* thr       = invn + S;
    int*   row_count = (int*)(thr + B);

    const int mx = (B > S) ? B : S;
    prep_kernel<<<(mx + 3) / 4, 256, 0, stream>>>(x1, x2, invn, thr, row_count, B, S);

    dim3 grid(S / BN, B / BM);
    count_kernel<<<grid, 256, 0, stream>>>(x1, x2, invn, thr, row_count, B, S);

    finalize_kernel<<<1, 1024, 0, stream>>>(row_count, (float*)d_out, B, nper);
}

// Round 2
// 136.040 us; speedup vs baseline: 2.2536x; 2.2536x over previous
//
#include <hip/hip_runtime.h>

// out = mean_i( rank_of_diag(cos_sim(x1,x2))_i < nper ), nper = S/100+1.
// rank_i = #{ j != i : dot(x1_i,x2_j)*inv||x2_j|| > dot(x1_i,x2_i)*inv||x2_i|| }
// GEMM via fp16x3 (Markidis split) MFMA: x=hi+lo; hi*hi + hi*lo + lo*hi.
// Dropped lo*lo ~2^-22 rel/term -> dot err ~3e-6 << 4.5e-3 order-stat spacing.

#define KDIM 128

typedef _Float16 half8 __attribute__((ext_vector_type(8)));
typedef float floatx16 __attribute__((ext_vector_type(16)));

// ---------- Kernel A: per-row 1/||x2||, diag threshold, zero counters ----------
__global__ __launch_bounds__(256) void prep_kernel(
    const float* __restrict__ x1, const float* __restrict__ x2,
    float* __restrict__ invn, float* __restrict__ thr,
    int* __restrict__ row_count, int B, int S)
{
    const int wave = threadIdx.x >> 6;
    const int lane = threadIdx.x & 63;
    const int row = blockIdx.x * 4 + wave;
    if (row >= S && row >= B) return;

    float s22 = 0.f, s12 = 0.f;
    if (row < S) {
        const float2* p1 = (const float2*)&x1[(size_t)row * KDIM];
        const float2* p2 = (const float2*)&x2[(size_t)row * KDIM];
        float2 a = p1[lane];
        float2 b = p2[lane];
        s22 = fmaf(b.x, b.x, b.y * b.y);
        s12 = fmaf(a.x, b.x, a.y * b.y);
    }
    #pragma unroll
    for (int m = 32; m > 0; m >>= 1) {
        s22 += __shfl_xor(s22, m);
        s12 += __shfl_xor(s12, m);
    }
    if (lane == 0) {
        if (row < S) {
            float iv = rsqrtf(s22);
            invn[row] = iv;
            if (row < B) thr[row] = s12 * iv;
        }
        if (row < B) row_count[row] = 0;
    }
}

// ---------- Kernel B: fp16x3 MFMA GEMM + compare-count ----------
// 128x128 tile, 4 waves of 64x64 (2x2 tiles of 32x32), BK=32 chunks.
// LDS planes stored FRAGMENT-ORDERED: block(rowgrp rg 0..3, ks2 0..1) of 1KB,
// lane l holds row m=l&31, k=(l>>5)*8+j  ->  offset = (rg*2+ks2)*512 + l*8 halves.
// Reads: fully lane-contiguous ds_read_b128 (0 conflicts). Writes: 2-way (free).
__global__ __launch_bounds__(256) void count_kernel(
    const float* __restrict__ x1, const float* __restrict__ x2,
    const float* __restrict__ invn, const float* __restrict__ thr,
    int* __restrict__ row_count)
{
    __shared__ __align__(16) _Float16 As_hi[4096], As_lo[4096];
    __shared__ __align__(16) _Float16 Bs_hi[4096], Bs_lo[4096];
    __shared__ float s_thr[128], s_invn[128];
    __shared__ int cnt_s[128];

    const int tid  = threadIdx.x;
    const int wave = tid >> 6;
    const int lane = tid & 63;
    const int row0 = blockIdx.y * 128;
    const int col0 = blockIdx.x * 128;
    const int wr = (wave >> 1) * 64;   // wave row offset
    const int wc = (wave & 1) * 64;    // wave col offset

    if (tid < 128) {
        cnt_s[tid]  = 0;
        s_thr[tid]  = thr[row0 + tid];
        s_invn[tid] = invn[col0 + tid];
    }

    floatx16 acc[2][2];
    #pragma unroll
    for (int a = 0; a < 2; a++)
        #pragma unroll
        for (int b = 0; b < 2; b++)
            #pragma unroll
            for (int i = 0; i < 16; i++) acc[a][b][i] = 0.f;

    // staging coords: thread covers (row sr, k-16-group sks2): 16 floats
    const int sr   = tid >> 1;       // 0..127
    const int sks2 = tid & 1;        // 0/1
    const int wbase = ((sr >> 5) * 2 + sks2) * 512 + (sr & 31) * 8; // hw=0 slot
    const size_t ga = (size_t)(row0 + sr) * KDIM + sks2 * 16;
    const size_t gb = (size_t)(col0 + sr) * KDIM + sks2 * 16;

    const int wrg = wr >> 5;         // A rowgroup base: 0 or 2
    const int wcg = wc >> 5;         // B rowgroup base: 0 or 2
    const int lane8 = lane * 8;

    for (int kc = 0; kc < KDIM; kc += 32) {
        __syncthreads();
        // ---- stage A chunk ----
        {
            const float* p = &x1[ga + kc];
            float v[16];
            *(float4*)&v[0]  = *(const float4*)(p);
            *(float4*)&v[4]  = *(const float4*)(p + 4);
            *(float4*)&v[8]  = *(const float4*)(p + 8);
            *(float4*)&v[12] = *(const float4*)(p + 12);
            half8 h0, h1, l0, l1;
            #pragma unroll
            for (int i = 0; i < 8; i++) {
                _Float16 h = (_Float16)v[i];
                h0[i] = h; l0[i] = (_Float16)(v[i] - (float)h);
                _Float16 g = (_Float16)v[i + 8];
                h1[i] = g; l1[i] = (_Float16)(v[i + 8] - (float)g);
            }
            *(half8*)&As_hi[wbase]       = h0;
            *(half8*)&As_hi[wbase + 256] = h1;
            *(half8*)&As_lo[wbase]       = l0;
            *(half8*)&As_lo[wbase + 256] = l1;
        }
        // ---- stage B chunk ----
        {
            const float* p = &x2[gb + kc];
            float v[16];
            *(float4*)&v[0]  = *(const float4*)(p);
            *(float4*)&v[4]  = *(const float4*)(p + 4);
            *(float4*)&v[8]  = *(const float4*)(p + 8);
            *(float4*)&v[12] = *(const float4*)(p + 12);
            half8 h0, h1, l0, l1;
            #pragma unroll
            for (int i = 0; i < 8; i++) {
                _Float16 h = (_Float16)v[i];
                h0[i] = h; l0[i] = (_Float16)(v[i] - (float)h);
                _Float16 g = (_Float16)v[i + 8];
                h1[i] = g; l1[i] = (_Float16)(v[i + 8] - (float)g);
            }
            *(half8*)&Bs_hi[wbase]       = h0;
            *(half8*)&Bs_hi[wbase + 256] = h1;
            *(half8*)&Bs_lo[wbase]       = l0;
            *(half8*)&Bs_lo[wbase + 256] = l1;
        }
        __syncthreads();

        // ---- MFMA over the two K=16 steps of this chunk ----
        #pragma unroll
        for (int ks2 = 0; ks2 < 2; ks2++) {
            half8 ah[2], al[2], bh[2], bl[2];
            #pragma unroll
            for (int t = 0; t < 2; t++) {
                const int oa = ((wrg + t) * 2 + ks2) * 512 + lane8;
                ah[t] = *(const half8*)&As_hi[oa];
                al[t] = *(const half8*)&As_lo[oa];
                const int ob = ((wcg + t) * 2 + ks2) * 512 + lane8;
                bh[t] = *(const half8*)&Bs_hi[ob];
                bl[t] = *(const half8*)&Bs_lo[ob];
            }
            #pragma unroll
            for (int mt = 0; mt < 2; mt++)
                #pragma unroll
                for (int nt = 0; nt < 2; nt++) {
                    acc[mt][nt] = __builtin_amdgcn_mfma_f32_32x32x16_f16(al[mt], bh[nt], acc[mt][nt], 0, 0, 0);
                    acc[mt][nt] = __builtin_amdgcn_mfma_f32_32x32x16_f16(ah[mt], bl[nt], acc[mt][nt], 0, 0, 0);
                    acc[mt][nt] = __builtin_amdgcn_mfma_f32_32x32x16_f16(ah[mt], bh[nt], acc[mt][nt], 0, 0, 0);
                }
        }
    }

    // ---- epilogue: normalize, compare vs diag threshold, ballot-count ----
    // C/D layout (32x32): col = lane&31, row = (reg&3) + 8*(reg>>2) + 4*(lane>>5)
    const int cm = lane & 31;
    const int hw = lane >> 5;
    const float iv0 = s_invn[wc + cm];
    const float iv1 = s_invn[wc + 32 + cm];
    const int gc0 = col0 + wc + cm;
    const int gc1 = gc0 + 32;

    #pragma unroll
    for (int mt = 0; mt < 2; mt++) {
        #pragma unroll
        for (int reg = 0; reg < 16; reg++) {
            const int rbase = wr + mt * 32 + (reg & 3) + 8 * (reg >> 2);
            const int rloc  = rbase + 4 * hw;
            const int grow  = row0 + rloc;
            const float t   = s_thr[rloc];
            const bool p0 = (acc[mt][0][reg] * iv0 > t) && (gc0 != grow);
            const bool p1 = (acc[mt][1][reg] * iv1 > t) && (gc1 != grow);
            const unsigned long long b0 = __ballot(p0);
            const unsigned long long b1 = __ballot(p1);
            if (lane == 0) {
                const int clo = __popcll(b0 & 0xffffffffULL) + __popcll(b1 & 0xffffffffULL);
                if (clo) atomicAdd(&cnt_s[rbase], clo);
            } else if (lane == 32) {
                const int chi = __popcll(b0 >> 32) + __popcll(b1 >> 32);
                if (chi) atomicAdd(&cnt_s[rbase + 4], chi);
            }
        }
    }
    __syncthreads();
    if (tid < 128) {
        const int v = cnt_s[tid];
        if (v) atomicAdd(&row_count[row0 + tid], v);
    }
}

// ---------- Kernel C: final reduction ----------
__global__ __launch_bounds__(1024) void finalize_kernel(
    const int* __restrict__ row_count, float* __restrict__ out, int B, int nper)
{
    __shared__ int wsum[16];
    const int t = threadIdx.x;
    int c = 0;
    for (int i = t; i < B; i += 1024) c += (row_count[i] < nper) ? 1 : 0;
    #pragma unroll
    for (int m = 32; m > 0; m >>= 1) c += __shfl_xor(c, m);
    if ((t & 63) == 0) wsum[t >> 6] = c;
    __syncthreads();
    if (t == 0) {
        int tot = 0;
        #pragma unroll
        for (int w = 0; w < 16; w++) tot += wsum[w];
        out[0] = (float)tot / (float)B;
    }
}

extern "C" void kernel_launch(void* const* d_in, const int* in_sizes, int n_in,
                              void* d_out, int out_size, void* d_ws, size_t ws_size,
                              hipStream_t stream)
{
    const float* x1 = (const float*)d_in[0];
    const float* x2 = (const float*)d_in[1];
    const int B = in_sizes[0] / KDIM;     // 8192
    const int S = in_sizes[1] / KDIM;     // 8192
    const int nper = S / 100 + 1;         // 82

    float* invn      = (float*)d_ws;
    float* thr       = invn + S;
    int*   row_count = (int*)(thr + B);

    const int mx = (B > S) ? B : S;
    prep_kernel<<<(mx + 3) / 4, 256, 0, stream>>>(x1, x2, invn, thr, row_count, B, S);

    dim3 grid(S / 128, B / 128);
    count_kernel<<<grid, 256, 0, stream>>>(x1, x2, invn, thr, row_count);

    finalize_kernel<<<1, 1024, 0, stream>>>(row_count, (float*)d_out, B, nper);
}